// Round 5
// baseline (1796.933 us; speedup 1.0000x reference)
//
#include <hip/hip_runtime.h>
#include <math.h>

#define N_TOKENS    16384
#define MODEL_DIM   2048
#define NUM_EXPERTS 64
#define NK          (N_TOKENS * 2)          // 32768

// d_out layout (float32 elements)
#define OFF_TOKEN_ORDER 0
#define OFF_REVERSED    (NK)                // 32768
#define OFF_COMBINE     (2 * NK)            // 65536
#define OFF_SPLITS      (3 * NK)            // 98304
#define OFF_PROBS       (3 * NK + NUM_EXPERTS)

#define BT 256           // tokens per gate block
#define BK 32            // k-tile (128B rows, 8 chunks of 16B)
#define NSEG 256         // sort segments (= reduce blocks), 128 slots each
#define LSTRIDE 65       // padded logits row in reduce kernel

// ---------------------------------------------------------------------------
// Kernel 1: split-K gate partials. grid (64 tb, S sp) x 256 threads.
// 8 tok x 8 exp per thread (256x64 block). ds_write staging (NO
// global_load_lds: round-4 showed swizzled per-lane addresses break DMA
// merging -> 851MB fetch / 1.4GB write). Swizzle: phys_chunk =
// (chunk + row/8) & 7, same structure round 3 measured at ~0 conflicts.
// fp32 accumulate over the k-slice; fp64 fold happens in reduce_kernel.
// ---------------------------------------------------------------------------
__global__ __launch_bounds__(256, 2) void gate_partial(
    const float* __restrict__ x,   // [N, D]
    const float* __restrict__ w,   // [E, D]
    float* __restrict__ partials,  // [64][S][256*64]
    int S, int kslice)
{
    __shared__ __align__(16) float a_tile[BT * BK];           // 32 KB
    __shared__ __align__(16) float b_tile[NUM_EXPERTS * BK];  // 8 KB

    const int tid = threadIdx.x;
    const int tb = blockIdx.x;      // 0..63
    const int sp = blockIdx.y;      // 0..S-1
    const int t0 = tb * BT;
    const int kbase = sp * kslice;
    const int wv = tid >> 6, ln = tid & 63;
    const int tx = tid & 7;         // expert group: experts tx*8 .. +7
    const int ty = tid >> 3;        // token group 0..31: tokens ty*8 .. +7

    const int srow = wv * 8 + (ln >> 3);   // staging row base (+32 per g)
    const int sch = ln & 7;                // staging logical chunk

    float acc[8][8];
#pragma unroll
    for (int i = 0; i < 8; i++)
#pragma unroll
        for (int j = 0; j < 8; j++) acc[i][j] = 0.0f;

    for (int k0 = kbase; k0 < kbase + kslice; k0 += BK) {
        // ---- stage A (256x32) and B (64x32), swizzled in LDS space ----
#pragma unroll
        for (int g = 0; g < 8; g++) {
            const int row = g * 32 + srow;
            const float4 v = *(const float4*)(x + (size_t)(t0 + row) * MODEL_DIM + k0 + sch * 4);
            const int phys = (sch + (row >> 3)) & 7;
            *(float4*)(a_tile + row * 32 + phys * 4) = v;
        }
#pragma unroll
        for (int g = 0; g < 2; g++) {
            const int row = g * 32 + srow;
            const float4 v = *(const float4*)(w + (size_t)row * MODEL_DIM + k0 + sch * 4);
            const int phys = (sch + (row >> 3)) & 7;
            *(float4*)(b_tile + row * 32 + phys * 4) = v;
        }
        __syncthreads();

        // ---- compute: 8 k4-steps, 16 ds_read_b128 per 256 FMA ----
#pragma unroll
        for (int k4 = 0; k4 < 8; k4++) {
            // token rows ty*8+i: row>>3 == ty -> phys = (k4+ty)&7
            const float* ap = a_tile + ty * 256 + ((k4 + ty) & 7) * 4;
            // expert rows tx*8+j: row>>3 == tx -> phys = (k4+tx)&7
            const float* bp = b_tile + tx * 256 + ((k4 + tx) & 7) * 4;
            float4 a[8];
#pragma unroll
            for (int i = 0; i < 8; i++) a[i] = *(const float4*)(ap + i * 32);
#pragma unroll
            for (int j = 0; j < 8; j++) {
                const float4 b = *(const float4*)(bp + j * 32);
#pragma unroll
                for (int i = 0; i < 8; i++)
                    acc[i][j] += a[i].x * b.x + a[i].y * b.y + a[i].z * b.z + a[i].w * b.w;
            }
        }
        __syncthreads();
    }

    // ---- store fp32 partials [token][expert] ----
    float* dst = partials + ((size_t)(tb * S + sp) * BT) * 64;
#pragma unroll
    for (int i = 0; i < 8; i++)
#pragma unroll
        for (int j4 = 0; j4 < 2; j4++) {
            float4 v;
            v.x = acc[i][j4 * 4 + 0]; v.y = acc[i][j4 * 4 + 1];
            v.z = acc[i][j4 * 4 + 2]; v.w = acc[i][j4 * 4 + 3];
            *(float4*)(dst + (ty * 8 + i) * 64 + tx * 8 + j4 * 4) = v;
        }
}

// ---------------------------------------------------------------------------
// Kernel 2: reduce split-K partials (fp64 sum) + softmax + top-2 + combine
//           + per-segment hist + probs. grid 256 blocks x 256 threads.
// ---------------------------------------------------------------------------
__global__ __launch_bounds__(256) void reduce_kernel(
    const float* __restrict__ partials,
    float* __restrict__ out,
    int* __restrict__ flat_idx,
    int* __restrict__ segHist,
    int S)
{
    __shared__ float l_lds[64 * LSTRIDE];
    __shared__ float inv_lds[64];
    __shared__ int hist[NUM_EXPERTS];

    const int tid = threadIdx.x;
    const int rb = blockIdx.x;              // 0..255, 64 tokens each
    const int t0 = rb * 64;
    // gate block = rb>>2 (256 tokens), quarter = rb&3
    const float* src = partials + (size_t)(rb >> 2) * S * (BT * 64)
                               + (size_t)(rb & 3) * 4096;

#pragma unroll
    for (int v = 0; v < 4; v++) {
        const int q = tid + v * 256;        // 0..1023: t = q>>4, c = (q&15)*4
        const int t = q >> 4;
        const int c = (q & 15) * 4;
        double a0 = 0.0, a1 = 0.0, a2 = 0.0, a3 = 0.0;
        for (int s = 0; s < S; s++) {
            const float4 p = *(const float4*)(src + (size_t)s * (BT * 64) + t * 64 + c);
            a0 += (double)p.x; a1 += (double)p.y; a2 += (double)p.z; a3 += (double)p.w;
        }
        float* row = l_lds + t * LSTRIDE + c;
        row[0] = (float)a0; row[1] = (float)a1; row[2] = (float)a2; row[3] = (float)a3;
    }
    if (tid < NUM_EXPERTS) hist[tid] = 0;
    __syncthreads();

    if (tid < 64) {
        const int t = tid;
        float* row = l_lds + t * LSTRIDE;
        float m = -INFINITY;
#pragma unroll
        for (int e = 0; e < NUM_EXPERTS; e++) m = fmaxf(m, row[e]);
        float l1 = -INFINITY, l2 = -INFINITY;
        int i1 = 0, i2 = 0;
        double s = 0.0;
        for (int e = 0; e < NUM_EXPERTS; e++) {
            const float l = row[e];
            if (l > l1) { l2 = l1; i2 = i1; l1 = l; i1 = e; }
            else if (l > l2) { l2 = l; i2 = e; }
            const float ex = expf(l - m);
            s += (double)ex;
            row[e] = ex;
        }
        const float inv = (float)(1.0 / s);
        inv_lds[t] = inv;
        const float p1 = expf(l1 - m) * inv;
        const float p2 = expf(l2 - m) * inv;
        const float e2 = expf(p2 - p1);
        const float r = 1.0f / (1.0f + e2);
        const int gtok = t0 + t;
        out[OFF_COMBINE + 2 * gtok]     = r;
        out[OFF_COMBINE + 2 * gtok + 1] = e2 * r;
        flat_idx[2 * gtok]     = i1;
        flat_idx[2 * gtok + 1] = i2;
        atomicAdd(&hist[i1], 1);
        atomicAdd(&hist[i2], 1);
    }
    __syncthreads();

    if (tid < NUM_EXPERTS) segHist[rb * NUM_EXPERTS + tid] = hist[tid];

    // coalesced probs write (also safely overwrites the S=1 in-place fallback)
#pragma unroll
    for (int r4 = 0; r4 < 4; r4++) {
        const int f = r4 * 1024 + tid * 4;
        const int t = f >> 6;
        const int e = f & 63;
        const float inv = inv_lds[t];
        float4 v;
        v.x = l_lds[t * LSTRIDE + e + 0] * inv;
        v.y = l_lds[t * LSTRIDE + e + 1] * inv;
        v.z = l_lds[t * LSTRIDE + e + 2] * inv;
        v.w = l_lds[t * LSTRIDE + e + 3] * inv;
        *(float4*)(out + OFF_PROBS + (size_t)(t0 + t) * NUM_EXPERTS + e) = v;
    }
}

// ---------------------------------------------------------------------------
// Kernel 3: scan segment hists. 2-level, 1 block x 256 threads.
// ---------------------------------------------------------------------------
__global__ __launch_bounds__(256) void scan_kernel(
    const int* __restrict__ segHist, int* __restrict__ segOff,
    float* __restrict__ out)
{
    __shared__ int h[NSEG * NUM_EXPERTS];   // 64 KB
    __shared__ int gtot[4 * NUM_EXPERTS];
    __shared__ int base[NUM_EXPERTS];
    const int tid = threadIdx.x;
    for (int i = tid; i < NSEG * NUM_EXPERTS / 4; i += 256)
        *(int4*)(h + i * 4) = *(const int4*)(segHist + i * 4);
    __syncthreads();

    const int e = tid & 63;
    const int g = tid >> 6;                 // 0..3
    int run = 0;
    for (int s = g * 64; s < g * 64 + 64; s++) {
        const int idx = s * NUM_EXPERTS + e;
        const int v = h[idx];
        h[idx] = run;
        run += v;
    }
    gtot[g * NUM_EXPERTS + e] = run;
    __syncthreads();

    if (tid < NUM_EXPERTS) {
        int b = 0;
#pragma unroll
        for (int gg = 0; gg < 4; gg++) {
            const int t = gtot[gg * NUM_EXPERTS + tid];
            gtot[gg * NUM_EXPERTS + tid] = b;
            b += t;
        }
        out[OFF_SPLITS + tid] = (float)b;
        int xs = b;                          // inclusive wave scan over experts
#pragma unroll
        for (int off = 1; off < 64; off <<= 1) {
            const int v = __shfl_up(xs, off);
            if (tid >= off) xs += v;
        }
        base[tid] = xs - b;                  // exclusive
    }
    __syncthreads();

    const int myoff = gtot[g * NUM_EXPERTS + e] + base[e];
    for (int s = g * 64; s < g * 64 + 64; s++) {
        const int idx = s * NUM_EXPERTS + e;
        segOff[idx] = h[idx] + myoff;
    }
}

// ---------------------------------------------------------------------------
// Kernel 4: stable scatter via ballot-match ranks (round-2/3 verified)
// ---------------------------------------------------------------------------
__global__ __launch_bounds__(256) void scatter_kernel(
    const int* __restrict__ flat_idx, const int* __restrict__ segOff,
    float* __restrict__ out)
{
    __shared__ int cnt[2 * NUM_EXPERTS];
    const int tid = threadIdx.x;
    const int i = blockIdx.x * 256 + tid;
    const int e = flat_idx[i];
    const int lane = tid & 63;
    const int wv = tid >> 6;
    const int segslot = wv >> 1;
    const int seg = i >> 7;

    if (tid < 2 * NUM_EXPERTS) cnt[tid] = 0;
    __syncthreads();

    unsigned long long match = ~0ull;
#pragma unroll
    for (int b = 0; b < 6; b++) {
        const unsigned long long m = __ballot((e >> b) & 1);
        match &= ((e >> b) & 1) ? m : ~m;
    }
    const int rank = __popcll(match & ((1ull << lane) - 1ull));

    int pos = 0;
    if ((wv & 1) == 0) {
        pos = segOff[seg * NUM_EXPERTS + e] + rank;
        if (lane == __builtin_ctzll(match))
            cnt[segslot * NUM_EXPERTS + e] = __popcll(match);
    }
    __syncthreads();
    if ((wv & 1) == 1)
        pos = segOff[seg * NUM_EXPERTS + e] + cnt[segslot * NUM_EXPERTS + e] + rank;

    out[OFF_TOKEN_ORDER + pos] = (float)(i >> 1);
    out[OFF_REVERSED + i]      = (float)pos;
}

// ---------------------------------------------------------------------------
extern "C" void kernel_launch(void* const* d_in, const int* in_sizes, int n_in,
                              void* d_out, int out_size, void* d_ws, size_t ws_size,
                              hipStream_t stream) {
    const float* x = (const float*)d_in[0];   // [16384, 2048] fp32
    const float* w = (const float*)d_in[1];   // [64, 2048] fp32
    float* out = (float*)d_out;

    int* flat_idx = (int*)d_ws;                          // NK ints
    int* segHist  = flat_idx + NK;                       // 256*64
    int* segOff   = segHist + NSEG * NUM_EXPERTS;        // 256*64
    float* ws_part = (float*)(segOff + NSEG * NUM_EXPERTS);

    const size_t fixed_bytes = ((size_t)NK + 2 * NSEG * NUM_EXPERTS) * 4;
    const size_t avail = ws_size > fixed_bytes ? ws_size - fixed_bytes : 0;
    const size_t part1 = (size_t)N_TOKENS * NUM_EXPERTS * 4;   // 4 MB per split

    int S;
    float* partials = ws_part;
    if      (avail >= 8 * part1) S = 8;
    else if (avail >= 4 * part1) S = 4;
    else if (avail >= 2 * part1) S = 2;
    else if (avail >= 1 * part1) S = 1;
    else { S = 1; partials = out + OFF_PROBS; }  // in-place fallback
    const int kslice = MODEL_DIM / S;

    gate_partial<<<dim3(N_TOKENS / BT, S), 256, 0, stream>>>(x, w, partials, S, kslice);
    reduce_kernel<<<NSEG, 256, 0, stream>>>(partials, out, flat_idx, segHist, S);
    scan_kernel<<<1, 256, 0, stream>>>(segHist, segOff, out);
    scatter_kernel<<<NK / 256, 256, 0, stream>>>(flat_idx, segOff, out);
}

// Round 6
// 595.431 us; speedup vs baseline: 3.0179x; 3.0179x over previous
//
#include <hip/hip_runtime.h>
#include <math.h>

#define N_TOKENS    16384
#define MODEL_DIM   2048
#define NUM_EXPERTS 64
#define NK          (N_TOKENS * 2)          // 32768

// d_out layout (float32 elements)
#define OFF_TOKEN_ORDER 0
#define OFF_REVERSED    (NK)                // 32768
#define OFF_COMBINE     (2 * NK)            // 65536
#define OFF_SPLITS      (3 * NK)            // 98304
#define OFF_PROBS       (3 * NK + NUM_EXPERTS)

#define BT 64            // tokens per gate block (= lanes of a wave)
#define BK 64            // k-tile (16 chunks of 16B per row)
#define NSEG 256         // sort segments (= reduce blocks), 128 slots each
#define LSTRIDE 65       // padded logits row in reduce kernel

// ---------------------------------------------------------------------------
// Kernel 1: split-K gate partials. grid (256 tb, S sp) x 256 threads.
// Wave-uniform expert mapping: wave w owns experts [w*16, w*16+16), lane =
// token. B is loaded via UNIFORM addresses -> s_load into SGPRs (legal SGPR
// src of v_fma_f32); B never touches LDS or VGPR vectors. A staged in LDS,
// 1 ds_read_b128 per lane per k4 (swizzle phys=(c+row)&15: 8 dwords/bank,
// optimal). Per k4 per thread: 1 LDS read + 64 FMA -> FMA-bound.
// fp32 accumulate over the k-slice (round-5-validated numerics); fp64 fold
// in reduce_kernel. NO min-waves launch bound (round 5: (256,2) -> 128-VGPR
// cap -> accumulator spill -> 4.9 GB scratch traffic).
// ---------------------------------------------------------------------------
__global__ __launch_bounds__(256) void gate_partial(
    const float* __restrict__ x,   // [N, D]
    const float* __restrict__ w,   // [E, D]
    float* __restrict__ partials,  // [256][S][64*64]
    int S, int kslice)
{
    __shared__ __align__(16) float a_tile[BT * BK];   // 16 KB, swizzled

    const int tid = threadIdx.x;
    const int tb = blockIdx.x;       // 0..255
    const int sp = blockIdx.y;       // 0..S-1
    const int t0 = tb * BT;
    const int kbase = sp * kslice;
    const int lane = tid & 63;       // token within block
    // wave's first expert — readfirstlane pins it scalar so B addrs are uniform
    const int e0 = __builtin_amdgcn_readfirstlane((tid >> 6) << 4);

    const int srow = tid >> 4;       // staging row 0..15 (+16 per g)
    const int sc = tid & 15;         // staging logical chunk 0..15

    float acc[16];
#pragma unroll
    for (int j = 0; j < 16; j++) acc[j] = 0.0f;

    for (int k0 = kbase; k0 < kbase + kslice; k0 += BK) {
        // ---- stage A (64 tokens x 64 k), swizzled ----
#pragma unroll
        for (int g = 0; g < 4; g++) {
            const int row = g * 16 + srow;
            const float4 v = *(const float4*)(x + (size_t)(t0 + row) * MODEL_DIM + k0 + sc * 4);
            const int phys = (sc + row) & 15;
            *(float4*)(a_tile + row * 64 + phys * 4) = v;
        }
        __syncthreads();

        // ---- compute: per k4, 1 ds_read_b128 + 16 scalar float4 B + 64 FMA ----
#pragma unroll
        for (int k4 = 0; k4 < 16; k4++) {
            const float4 a = *(const float4*)(a_tile + lane * 64 + ((k4 + lane) & 15) * 4);
#pragma unroll
            for (int j = 0; j < 16; j++) {
                // uniform address -> s_load_dwordx4; SGPR operand in v_fma
                const float4 b = *(const float4*)(w + (size_t)(e0 + j) * MODEL_DIM + k0 + k4 * 4);
                acc[j] += a.x * b.x + a.y * b.y + a.z * b.z + a.w * b.w;
            }
        }
        __syncthreads();
    }

    // ---- store fp32 partials [token][expert] ----
    float* dst = partials + ((size_t)(tb * S + sp) * BT) * 64 + lane * 64 + e0;
#pragma unroll
    for (int j4 = 0; j4 < 4; j4++) {
        float4 v;
        v.x = acc[j4 * 4 + 0]; v.y = acc[j4 * 4 + 1];
        v.z = acc[j4 * 4 + 2]; v.w = acc[j4 * 4 + 3];
        *(float4*)(dst + j4 * 4) = v;
    }
}

// ---------------------------------------------------------------------------
// Kernel 2: reduce split-K partials (fp64 sum) + softmax + top-2 + combine
//           + per-segment hist + probs. grid 256 blocks x 256 threads.
//           (round-3 verified, unchanged)
// ---------------------------------------------------------------------------
__global__ __launch_bounds__(256) void reduce_kernel(
    const float* __restrict__ partials,
    float* __restrict__ out,
    int* __restrict__ flat_idx,
    int* __restrict__ segHist,
    int S)
{
    __shared__ float l_lds[BT * LSTRIDE];
    __shared__ float inv_lds[BT];
    __shared__ int hist[NUM_EXPERTS];

    const int tid = threadIdx.x;
    const int tb = blockIdx.x;
    const int t0 = tb * BT;
    const float* src = partials + (size_t)tb * S * 4096;

#pragma unroll
    for (int v = 0; v < 4; v++) {
        const int q = tid + v * 256;            // float4 index 0..1023
        double a0 = 0.0, a1 = 0.0, a2 = 0.0, a3 = 0.0;
        for (int s = 0; s < S; s++) {
            const float4 p = *(const float4*)(src + (size_t)s * 4096 + q * 4);
            a0 += (double)p.x; a1 += (double)p.y; a2 += (double)p.z; a3 += (double)p.w;
        }
        const int f = q * 4;
        const int t = f >> 6;
        const int e = f & 63;
        float* row = l_lds + t * LSTRIDE + e;
        row[0] = (float)a0; row[1] = (float)a1; row[2] = (float)a2; row[3] = (float)a3;
    }
    if (tid < NUM_EXPERTS) hist[tid] = 0;
    __syncthreads();

    if (tid < BT) {
        const int t = tid;
        float* row = l_lds + t * LSTRIDE;
        float m = -INFINITY;
#pragma unroll
        for (int e = 0; e < NUM_EXPERTS; e++) m = fmaxf(m, row[e]);
        float l1 = -INFINITY, l2 = -INFINITY;
        int i1 = 0, i2 = 0;
        double s = 0.0;
        for (int e = 0; e < NUM_EXPERTS; e++) {
            const float l = row[e];
            if (l > l1) { l2 = l1; i2 = i1; l1 = l; i1 = e; }
            else if (l > l2) { l2 = l; i2 = e; }
            const float ex = expf(l - m);
            s += (double)ex;
            row[e] = ex;
        }
        const float inv = (float)(1.0 / s);
        inv_lds[t] = inv;
        const float p1 = expf(l1 - m) * inv;
        const float p2 = expf(l2 - m) * inv;
        const float e2 = expf(p2 - p1);
        const float r = 1.0f / (1.0f + e2);
        const int gtok = t0 + t;
        out[OFF_COMBINE + 2 * gtok]     = r;
        out[OFF_COMBINE + 2 * gtok + 1] = e2 * r;
        flat_idx[2 * gtok]     = i1;
        flat_idx[2 * gtok + 1] = i2;
        atomicAdd(&hist[i1], 1);
        atomicAdd(&hist[i2], 1);
    }
    __syncthreads();

    if (tid < NUM_EXPERTS) segHist[tb * NUM_EXPERTS + tid] = hist[tid];

    // coalesced probs write (also safely overwrites the S=1 in-place fallback)
#pragma unroll
    for (int r4 = 0; r4 < 4; r4++) {
        const int f = r4 * 1024 + tid * 4;
        const int t = f >> 6;
        const int e = f & 63;
        const float inv = inv_lds[t];
        float4 v;
        v.x = l_lds[t * LSTRIDE + e + 0] * inv;
        v.y = l_lds[t * LSTRIDE + e + 1] * inv;
        v.z = l_lds[t * LSTRIDE + e + 2] * inv;
        v.w = l_lds[t * LSTRIDE + e + 3] * inv;
        *(float4*)(out + OFF_PROBS + (size_t)(t0 + t) * NUM_EXPERTS + e) = v;
    }
}

// ---------------------------------------------------------------------------
// Kernel 3: scan segment hists. 2-level, 1 block x 256 threads. (unchanged)
// ---------------------------------------------------------------------------
__global__ __launch_bounds__(256) void scan_kernel(
    const int* __restrict__ segHist, int* __restrict__ segOff,
    float* __restrict__ out)
{
    __shared__ int h[NSEG * NUM_EXPERTS];   // 64 KB
    __shared__ int gtot[4 * NUM_EXPERTS];
    __shared__ int base[NUM_EXPERTS];
    const int tid = threadIdx.x;
    for (int i = tid; i < NSEG * NUM_EXPERTS / 4; i += 256)
        *(int4*)(h + i * 4) = *(const int4*)(segHist + i * 4);
    __syncthreads();

    const int e = tid & 63;
    const int g = tid >> 6;                 // 0..3
    int run = 0;
    for (int s = g * 64; s < g * 64 + 64; s++) {
        const int idx = s * NUM_EXPERTS + e;
        const int v = h[idx];
        h[idx] = run;
        run += v;
    }
    gtot[g * NUM_EXPERTS + e] = run;
    __syncthreads();

    if (tid < NUM_EXPERTS) {
        int b = 0;
#pragma unroll
        for (int gg = 0; gg < 4; gg++) {
            const int t = gtot[gg * NUM_EXPERTS + tid];
            gtot[gg * NUM_EXPERTS + tid] = b;
            b += t;
        }
        out[OFF_SPLITS + tid] = (float)b;
        int xs = b;                          // inclusive wave scan over experts
#pragma unroll
        for (int off = 1; off < 64; off <<= 1) {
            const int v = __shfl_up(xs, off);
            if (tid >= off) xs += v;
        }
        base[tid] = xs - b;                  // exclusive
    }
    __syncthreads();

    const int myoff = gtot[g * NUM_EXPERTS + e] + base[e];
    for (int s = g * 64; s < g * 64 + 64; s++) {
        const int idx = s * NUM_EXPERTS + e;
        segOff[idx] = h[idx] + myoff;
    }
}

// ---------------------------------------------------------------------------
// Kernel 4: stable scatter via ballot-match ranks (round-2/3 verified)
// ---------------------------------------------------------------------------
__global__ __launch_bounds__(256) void scatter_kernel(
    const int* __restrict__ flat_idx, const int* __restrict__ segOff,
    float* __restrict__ out)
{
    __shared__ int cnt[2 * NUM_EXPERTS];
    const int tid = threadIdx.x;
    const int i = blockIdx.x * 256 + tid;
    const int e = flat_idx[i];
    const int lane = tid & 63;
    const int wv = tid >> 6;
    const int segslot = wv >> 1;
    const int seg = i >> 7;

    if (tid < 2 * NUM_EXPERTS) cnt[tid] = 0;
    __syncthreads();

    unsigned long long match = ~0ull;
#pragma unroll
    for (int b = 0; b < 6; b++) {
        const unsigned long long m = __ballot((e >> b) & 1);
        match &= ((e >> b) & 1) ? m : ~m;
    }
    const int rank = __popcll(match & ((1ull << lane) - 1ull));

    int pos = 0;
    if ((wv & 1) == 0) {
        pos = segOff[seg * NUM_EXPERTS + e] + rank;
        if (lane == __builtin_ctzll(match))
            cnt[segslot * NUM_EXPERTS + e] = __popcll(match);
    }
    __syncthreads();
    if ((wv & 1) == 1)
        pos = segOff[seg * NUM_EXPERTS + e] + cnt[segslot * NUM_EXPERTS + e] + rank;

    out[OFF_TOKEN_ORDER + pos] = (float)(i >> 1);
    out[OFF_REVERSED + i]      = (float)pos;
}

// ---------------------------------------------------------------------------
extern "C" void kernel_launch(void* const* d_in, const int* in_sizes, int n_in,
                              void* d_out, int out_size, void* d_ws, size_t ws_size,
                              hipStream_t stream) {
    const float* x = (const float*)d_in[0];   // [16384, 2048] fp32
    const float* w = (const float*)d_in[1];   // [64, 2048] fp32
    float* out = (float*)d_out;

    int* flat_idx = (int*)d_ws;                          // NK ints
    int* segHist  = flat_idx + NK;                       // 256*64
    int* segOff   = segHist + NSEG * NUM_EXPERTS;        // 256*64
    float* ws_part = (float*)(segOff + NSEG * NUM_EXPERTS);

    const size_t fixed_bytes = ((size_t)NK + 2 * NSEG * NUM_EXPERTS) * 4;
    const size_t avail = ws_size > fixed_bytes ? ws_size - fixed_bytes : 0;
    const size_t part1 = (size_t)N_TOKENS * NUM_EXPERTS * 4;   // 4 MB per split

    int S;
    float* partials = ws_part;
    if      (avail >= 8 * part1) S = 8;
    else if (avail >= 4 * part1) S = 4;
    else if (avail >= 2 * part1) S = 2;
    else if (avail >= 1 * part1) S = 1;
    else { S = 1; partials = out + OFF_PROBS; }  // in-place fallback
    const int kslice = MODEL_DIM / S;

    gate_partial<<<dim3(N_TOKENS / BT, S), 256, 0, stream>>>(x, w, partials, S, kslice);
    reduce_kernel<<<NSEG, 256, 0, stream>>>(partials, out, flat_idx, segHist, S);
    scan_kernel<<<1, 256, 0, stream>>>(segHist, segOff, out);
    scatter_kernel<<<NK / 256, 256, 0, stream>>>(flat_idx, segOff, out);
}